// Round 2
// baseline (80018.219 us; speedup 1.0000x reference)
//
#include <hip/hip_runtime.h>
#include <hip/hip_bf16.h>
#include <hip/hip_fp16.h>

#define VOCABN 50257
#define EMBEDN 256
#define HIDDENN 256
#define TAGSN 8192
#define SEQN 8192

typedef _Float16 f16x2 __attribute__((ext_vector_type(2)));

__device__ __forceinline__ float fdot2(f16x2 a, f16x2 b, float c) {
#if __has_builtin(__builtin_amdgcn_fdot2)
    return __builtin_amdgcn_fdot2(a, b, c, false);
#else
    return c + (float)a[0] * (float)b[0] + (float)a[1] * (float)b[1];
#endif
}

__device__ __forceinline__ f16x2 bc16(unsigned int u) {
    return __builtin_bit_cast(f16x2, u);
}

__device__ __forceinline__ float sigm(float x) {
    x = fminf(fmaxf(x, -30.f), 30.f);
    return 1.f / (1.f + __expf(-x));
}

__device__ __forceinline__ float tanh_f(float x) {
    x = fminf(fmaxf(x, -15.f), 15.f);
    float e = __expf(-2.f * x);
    return (1.f - e) / (1.f + e);
}

// ---------------------------------------------------------------------------
// prep: WxT[k][o] = W_gate(o)[o&255][k]  (transposed x-part for coalesced GEMM)
//       bcat[o]   = b_gate(o)[o&255]
// ---------------------------------------------------------------------------
__global__ __launch_bounds__(256) void prep_kernel(
    const float* __restrict__ Wf, const float* __restrict__ Wi,
    const float* __restrict__ Wg, const float* __restrict__ Wo,
    const float* __restrict__ bf, const float* __restrict__ bi,
    const float* __restrict__ bg, const float* __restrict__ bo,
    float* __restrict__ WxT, float* __restrict__ bcat)
{
    int idx = blockIdx.x * 256 + threadIdx.x;   // 0..262143
    int k = idx >> 10, o = idx & 1023;
    int g = o >> 8, r = o & 255;
    const float* W = (g == 0) ? Wf : (g == 1) ? Wi : (g == 2) ? Wg : Wo;
    WxT[idx] = W[r * 512 + k];
    if (idx < 1024) {
        const float* b = (g == 0) ? bf : (g == 1) ? bi : (g == 2) ? bg : bo;
        bcat[idx] = b[r];
    }
}

// ---------------------------------------------------------------------------
// xproj[s][o] = sum_k emb[sentence[s]][k] * WxT[k][o] + bcat[o]
// ---------------------------------------------------------------------------
__global__ __launch_bounds__(256) void xproj_kernel(
    const int* __restrict__ sentence, const float* __restrict__ emb,
    const float* __restrict__ WxT, const float* __restrict__ bcat,
    float* __restrict__ xproj)
{
    __shared__ __align__(16) float At[32 * 256];
    const int tid = threadIdx.x;
    const int s0 = blockIdx.y * 32;
    const int o = blockIdx.x * 256 + tid;

#pragma unroll
    for (int i = 0; i < 32; i++) {
        int idx = tid + i * 256;
        int srow = idx >> 8, c = idx & 255;
        At[idx] = emb[(size_t)sentence[s0 + srow] * 256 + c];
    }
    __syncthreads();

    float acc[32];
    float b = bcat[o];
#pragma unroll
    for (int i = 0; i < 32; i++) acc[i] = b;

    for (int k4 = 0; k4 < 64; k4++) {
        float4 w;
        w.x = WxT[(k4 * 4 + 0) * 1024 + o];
        w.y = WxT[(k4 * 4 + 1) * 1024 + o];
        w.z = WxT[(k4 * 4 + 2) * 1024 + o];
        w.w = WxT[(k4 * 4 + 3) * 1024 + o];
#pragma unroll
        for (int i = 0; i < 32; i++) {
            float4 a = *(const float4*)&At[i * 256 + k4 * 4];
            acc[i] += a.x * w.x + a.y * w.y + a.z * w.z + a.w * w.w;
        }
    }
#pragma unroll
    for (int i = 0; i < 32; i++)
        xproj[(size_t)(s0 + i) * 1024 + o] = acc[i];
}

// ---------------------------------------------------------------------------
// Persistent single-workgroup LSTM. 512 threads (8 waves, 2 waves/SIMD).
// Thread t<256 owns gates (f,i) of unit t; thread t>=256 owns (g,o) of unit
// t-256. Per gate: h-dims [0,192) in 96 packed f16x2 VGPRs (2x96=192 regs),
// dims [192,256) in LDS chunk-major (128 KiB). waves_per_eu pinned to 2 so
// the allocator budgets 256 VGPRs -> no spill (round-1 failure: VGPR=64).
// ---------------------------------------------------------------------------
__global__ __launch_bounds__(512)
__attribute__((amdgpu_waves_per_eu(2, 2)))
void lstm_kernel(
    const float* __restrict__ Wf, const float* __restrict__ Wi,
    const float* __restrict__ Wg, const float* __restrict__ Wo,
    const float* __restrict__ xproj, float* __restrict__ h_all)
{
    __shared__ uint4 wlds[16][512];                 // 128 KiB, conflict-free b128
    __shared__ float gates[1024];                   // 4 KiB
    __shared__ __align__(16) _Float16 hbuf[2][256]; // 1 KiB double-buffered h

    const int t = threadIdx.x;
    const int r = t & 255;
    const bool lo = (t < 256);
    const float* WA = lo ? Wf : Wg;
    const float* WB = lo ? Wi : Wo;
    const float* rowA = WA + r * 512 + 256;         // h-part of the row
    const float* rowB = WB + r * 512 + 256;

    // ---- one-time setup ----
    f16x2 wA[96], wB[96];
#pragma unroll
    for (int j = 0; j < 96; j++) {
        float2 a2 = ((const float2*)rowA)[j];
        float2 b2 = ((const float2*)rowB)[j];
        wA[j] = f16x2{(_Float16)a2.x, (_Float16)a2.y};
        wB[j] = f16x2{(_Float16)b2.x, (_Float16)b2.y};
    }
#pragma unroll
    for (int c = 0; c < 8; c++) {                   // dims [192+8c, 192+8c+8)
        uint4 ua, ub;
        unsigned int* upa = (unsigned int*)&ua;
        unsigned int* upb = (unsigned int*)&ub;
#pragma unroll
        for (int q = 0; q < 4; q++) {
            float2 a2 = ((const float2*)rowA)[96 + c * 4 + q];
            float2 b2 = ((const float2*)rowB)[96 + c * 4 + q];
            upa[q] = __builtin_bit_cast(unsigned int, f16x2{(_Float16)a2.x, (_Float16)a2.y});
            upb[q] = __builtin_bit_cast(unsigned int, f16x2{(_Float16)b2.x, (_Float16)b2.y});
        }
        wlds[2 * c + 0][t] = ua;
        wlds[2 * c + 1][t] = ub;
    }
    if (lo) { hbuf[0][t] = (_Float16)0.f; hbuf[1][t] = (_Float16)0.f; }
    float cst = 0.f;
    __syncthreads();

    const int oA = lo ? t : (256 + t);              // gate-A output index
    const int oB = oA + 256;                        // gate-B output index

    for (int s = 0; s < SEQN; ++s) {
        const float* xr = xproj + (size_t)s * 1024;
        float xpA = xr[oA];
        float xpB = xr[oB];
        const uint4* hv = (const uint4*)hbuf[s & 1];

        float aA0 = 0.f, aA1 = 0.f, aB0 = 0.f, aB1 = 0.f;
#pragma unroll
        for (int c = 0; c < 24; c++) {              // dims [0,192): register weights
            uint4 h4 = hv[c];
            aA0 = fdot2(wA[4 * c + 0], bc16(h4.x), aA0);
            aA1 = fdot2(wA[4 * c + 1], bc16(h4.y), aA1);
            aA0 = fdot2(wA[4 * c + 2], bc16(h4.z), aA0);
            aA1 = fdot2(wA[4 * c + 3], bc16(h4.w), aA1);
            aB0 = fdot2(wB[4 * c + 0], bc16(h4.x), aB0);
            aB1 = fdot2(wB[4 * c + 1], bc16(h4.y), aB1);
            aB0 = fdot2(wB[4 * c + 2], bc16(h4.z), aB0);
            aB1 = fdot2(wB[4 * c + 3], bc16(h4.w), aB1);
        }
#pragma unroll
        for (int c = 0; c < 8; c++) {               // dims [192,256): LDS weights
            uint4 h4 = hv[24 + c];
            uint4 wa4 = wlds[2 * c + 0][t];
            uint4 wb4 = wlds[2 * c + 1][t];
            aA0 = fdot2(bc16(wa4.x), bc16(h4.x), aA0);
            aA1 = fdot2(bc16(wa4.y), bc16(h4.y), aA1);
            aA0 = fdot2(bc16(wa4.z), bc16(h4.z), aA0);
            aA1 = fdot2(bc16(wa4.w), bc16(h4.w), aA1);
            aB0 = fdot2(bc16(wb4.x), bc16(h4.x), aB0);
            aB1 = fdot2(bc16(wb4.y), bc16(h4.y), aB1);
            aB0 = fdot2(bc16(wb4.z), bc16(h4.z), aB0);
            aB1 = fdot2(bc16(wb4.w), bc16(h4.w), aB1);
        }
        float aA = aA0 + aA1 + xpA;
        float aB = aB0 + aB1 + xpB;
        float actA = lo ? sigm(aA) : tanh_f(aA);    // f (lo) / g (hi)
        float actB = sigm(aB);                      // i (lo) / o (hi)
        gates[oA] = actA;
        gates[oB] = actB;
        __syncthreads();
        if (lo) {
            float fg = gates[r], ig = gates[r + 256], gg = gates[r + 512], og = gates[r + 768];
            cst = fg * cst + ig * gg;
            float h = og * tanh_f(cst);
            h_all[s * 256 + r] = h;
            hbuf[(s + 1) & 1][r] = (_Float16)h;
        }
        __syncthreads();
    }
}

// ---------------------------------------------------------------------------
// logits[t][v] = h_all[t] . Wtag[v] + btag[v]   (64x64 tile / block, 4x4 micro)
// ---------------------------------------------------------------------------
__global__ __launch_bounds__(256) void logits_kernel(
    const float* __restrict__ h_all, const float* __restrict__ Wtag,
    const float* __restrict__ btag, float* __restrict__ out)
{
    __shared__ __align__(16) float At[64 * 68];
    __shared__ __align__(16) float Bt[64 * 68];
    const int tid = threadIdx.x;
    const int tx = tid & 15, ty = tid >> 4;
    const int t0 = blockIdx.y * 64, v0 = blockIdx.x * 64;
    float acc[4][4] = {};

    for (int kc = 0; kc < 256; kc += 64) {
        __syncthreads();
#pragma unroll
        for (int i = 0; i < 16; i++) {
            int idx = tid + i * 256;
            int rrow = idx >> 6, ccol = idx & 63;
            At[rrow * 68 + ccol] = h_all[(t0 + rrow) * 256 + kc + ccol];
            Bt[rrow * 68 + ccol] = Wtag[(size_t)(v0 + rrow) * 256 + kc + ccol];
        }
        __syncthreads();
#pragma unroll
        for (int k4 = 0; k4 < 16; k4++) {
            float4 av[4], bv[4];
#pragma unroll
            for (int i = 0; i < 4; i++) av[i] = *(const float4*)&At[(ty + 16 * i) * 68 + k4 * 4];
#pragma unroll
            for (int j = 0; j < 4; j++) bv[j] = *(const float4*)&Bt[(tx + 16 * j) * 68 + k4 * 4];
#pragma unroll
            for (int i = 0; i < 4; i++)
#pragma unroll
                for (int j = 0; j < 4; j++)
                    acc[i][j] += av[i].x * bv[j].x + av[i].y * bv[j].y +
                                 av[i].z * bv[j].z + av[i].w * bv[j].w;
        }
    }
#pragma unroll
    for (int j = 0; j < 4; j++) {
        float bb = btag[v0 + tx + 16 * j];
#pragma unroll
        for (int i = 0; i < 4; i++) {
            out[(size_t)(t0 + ty + 16 * i) * TAGSN + v0 + tx + 16 * j] = acc[i][j] + bb;
        }
    }
}

// ---------------------------------------------------------------------------
// in-place row-wise log_softmax over 8192 columns (one block per row)
// ---------------------------------------------------------------------------
__global__ __launch_bounds__(256) void lsm_kernel(float* __restrict__ out)
{
    const int row = blockIdx.x, tid = threadIdx.x;
    float* p = out + (size_t)row * TAGSN;
    float v[32];
#pragma unroll
    for (int j = 0; j < 32; j++) v[j] = p[tid + 256 * j];

    float m = -1e30f;
#pragma unroll
    for (int j = 0; j < 32; j++) m = fmaxf(m, v[j]);
#pragma unroll
    for (int off = 32; off; off >>= 1) m = fmaxf(m, __shfl_xor(m, off, 64));
    __shared__ float red[4];
    if ((tid & 63) == 0) red[tid >> 6] = m;
    __syncthreads();
    m = fmaxf(fmaxf(red[0], red[1]), fmaxf(red[2], red[3]));

    float s = 0.f;
#pragma unroll
    for (int j = 0; j < 32; j++) s += __expf(v[j] - m);
#pragma unroll
    for (int off = 32; off; off >>= 1) s += __shfl_xor(s, off, 64);
    __shared__ float red2[4];
    if ((tid & 63) == 0) red2[tid >> 6] = s;
    __syncthreads();
    s = (red2[0] + red2[1]) + (red2[2] + red2[3]);

    float lse = m + __logf(s);
#pragma unroll
    for (int j = 0; j < 32; j++) p[tid + 256 * j] = v[j] - lse;
}

// ---------------------------------------------------------------------------
extern "C" void kernel_launch(void* const* d_in, const int* in_sizes, int n_in,
                              void* d_out, int out_size, void* d_ws, size_t ws_size,
                              hipStream_t stream)
{
    const int*   sentence = (const int*)d_in[0];
    const float* emb  = (const float*)d_in[1];
    const float* Wf   = (const float*)d_in[2];
    const float* bf   = (const float*)d_in[3];
    const float* Wi   = (const float*)d_in[4];
    const float* bi   = (const float*)d_in[5];
    const float* Wg   = (const float*)d_in[6];
    const float* bg   = (const float*)d_in[7];
    const float* Wo   = (const float*)d_in[8];
    const float* bo   = (const float*)d_in[9];
    const float* Wtag = (const float*)d_in[10];
    const float* btag = (const float*)d_in[11];
    float* out = (float*)d_out;

    char* ws = (char*)d_ws;
    float* WxT   = (float*)(ws);                                      // 1 MiB
    float* bcat  = (float*)(ws + (1u << 20));                         // 4 KiB
    float* xproj = (float*)(ws + (1u << 20) + (1u << 16));            // 32 MiB
    float* h_all = (float*)(ws + (1u << 20) + (1u << 16) + (32u << 20)); // 8 MiB

    prep_kernel<<<1024, 256, 0, stream>>>(Wf, Wi, Wg, Wo, bf, bi, bg, bo, WxT, bcat);
    xproj_kernel<<<dim3(4, 256), 256, 0, stream>>>(sentence, emb, WxT, bcat, xproj);
    lstm_kernel<<<1, 512, 0, stream>>>(Wf, Wi, Wg, Wo, xproj, h_all);
    logits_kernel<<<dim3(128, 128), 256, 0, stream>>>(h_all, Wtag, btag, out);
    lsm_kernel<<<8192, 256, 0, stream>>>(out);
}

// Round 3
// 20048.985 us; speedup vs baseline: 3.9911x; 3.9911x over previous
//
#include <hip/hip_runtime.h>
#include <hip/hip_bf16.h>
#include <hip/hip_fp16.h>

#define VOCABN 50257
#define EMBEDN 256
#define HIDDENN 256
#define TAGSN 8192
#define SEQN 8192

typedef _Float16 half8 __attribute__((ext_vector_type(8)));
typedef float f32x4 __attribute__((ext_vector_type(4)));

__device__ __forceinline__ float sigm(float x) {
    x = fminf(fmaxf(x, -30.f), 30.f);
    return 1.f / (1.f + __expf(-x));
}

__device__ __forceinline__ float tanh_f(float x) {
    x = fminf(fmaxf(x, -15.f), 15.f);
    float e = __expf(-2.f * x);
    return (1.f - e) / (1.f + e);
}

// ---------------------------------------------------------------------------
// prep: WxT[k][o] = W_gate(o)[o&255][k]  (transposed x-part for coalesced GEMM)
//       bcat[o]   = b_gate(o)[o&255]
// ---------------------------------------------------------------------------
__global__ __launch_bounds__(256) void prep_kernel(
    const float* __restrict__ Wf, const float* __restrict__ Wi,
    const float* __restrict__ Wg, const float* __restrict__ Wo,
    const float* __restrict__ bf, const float* __restrict__ bi,
    const float* __restrict__ bg, const float* __restrict__ bo,
    float* __restrict__ WxT, float* __restrict__ bcat)
{
    int idx = blockIdx.x * 256 + threadIdx.x;   // 0..262143
    int k = idx >> 10, o = idx & 1023;
    int g = o >> 8, r = o & 255;
    const float* W = (g == 0) ? Wf : (g == 1) ? Wi : (g == 2) ? Wg : Wo;
    WxT[idx] = W[r * 512 + k];
    if (idx < 1024) {
        const float* b = (g == 0) ? bf : (g == 1) ? bi : (g == 2) ? bg : bo;
        bcat[idx] = b[r];
    }
}

// ---------------------------------------------------------------------------
// xproj[s][o] = sum_k emb[sentence[s]][k] * WxT[k][o] + bcat[o]
// ---------------------------------------------------------------------------
__global__ __launch_bounds__(256) void xproj_kernel(
    const int* __restrict__ sentence, const float* __restrict__ emb,
    const float* __restrict__ WxT, const float* __restrict__ bcat,
    float* __restrict__ xproj)
{
    __shared__ __align__(16) float At[32 * 256];
    const int tid = threadIdx.x;
    const int s0 = blockIdx.y * 32;
    const int o = blockIdx.x * 256 + tid;

#pragma unroll
    for (int i = 0; i < 32; i++) {
        int idx = tid + i * 256;
        int srow = idx >> 8, c = idx & 255;
        At[idx] = emb[(size_t)sentence[s0 + srow] * 256 + c];
    }
    __syncthreads();

    float acc[32];
    float b = bcat[o];
#pragma unroll
    for (int i = 0; i < 32; i++) acc[i] = b;

    for (int k4 = 0; k4 < 64; k4++) {
        float4 w;
        w.x = WxT[(k4 * 4 + 0) * 1024 + o];
        w.y = WxT[(k4 * 4 + 1) * 1024 + o];
        w.z = WxT[(k4 * 4 + 2) * 1024 + o];
        w.w = WxT[(k4 * 4 + 3) * 1024 + o];
#pragma unroll
        for (int i = 0; i < 32; i++) {
            float4 a = *(const float4*)&At[i * 256 + k4 * 4];
            acc[i] += a.x * w.x + a.y * w.y + a.z * w.z + a.w * w.w;
        }
    }
#pragma unroll
    for (int i = 0; i < 32; i++)
        xproj[(size_t)(s0 + i) * 1024 + o] = acc[i];
}

// ---------------------------------------------------------------------------
// Persistent single-workgroup LSTM via MFMA (16x16x32 f16).
// 512 threads = 8 waves. Wave w owns units [32w, 32w+32) x all 4 gates
// = 8 output tiles of 16 rows. K = 256 = 8 k-tiles of 32:
//   k-tiles 0..5 : A-frags in registers (8 tiles x 6 kt x 4 VGPR = 192; MFMA
//                  reads A from AGPR natively -> allocator-friendly)
//   k-tiles 6..7 : A-frags in LDS, frag-major (lane-linear, conflict-free)
// B-operand = h broadcast to all 16 cols: B[k][c] = h[k]; per-lane 16B read
// from hbuf (16-lane groups share an address -> cheap).
// D layout (HW-verified): col = lane&15 (replicated), row = (lane>>4)*4 + reg.
// xproj folds in as the accumulator init (16B global gather per tile).
// ---------------------------------------------------------------------------
__global__ __launch_bounds__(512, 2) void lstm_kernel(
    const float* __restrict__ Wf, const float* __restrict__ Wi,
    const float* __restrict__ Wg, const float* __restrict__ Wo,
    const float* __restrict__ xproj, float* __restrict__ h_all)
{
    __shared__ __align__(16) _Float16 wlds[128 * 512];   // 128 KiB frag-major A (kt 6,7)
    __shared__ __align__(16) _Float16 hbufF[2][256];     // 1 KiB  dbuf h (f16)
    __shared__ __align__(16) float preF[4 * 256];        // 4 KiB  raw->act exchange

    const int t = threadIdx.x;
    const int w = t >> 6;          // wave 0..7
    const int l = t & 63;          // lane
    const int row16 = l & 15;      // A row / D col
    const int kg = l >> 4;         // k-group 0..3

    const float* Wgate[4] = {Wf, Wi, Wg, Wo};

    // ---- one-time setup: A-frags into regs (kt<6) and LDS (kt 6,7) ----
    half8 Areg[48];                // [tile i][kt] = Areg[i*6+kt]
#pragma unroll
    for (int i = 0; i < 8; i++) {
        const int g = i >> 1, p = i & 1;
        const int row = 32 * w + 16 * p + row16;
        const float* base = Wgate[g] + row * 512 + 256 + 8 * kg;
#pragma unroll
        for (int kt = 0; kt < 8; kt++) {
            const float* src = base + kt * 32;
            half8 fr;
#pragma unroll
            for (int j = 0; j < 8; j++) fr[j] = (_Float16)src[j];
            if (kt < 6) {
                Areg[i * 6 + kt] = fr;
            } else {
                *(half8*)&wlds[(w * 16 + i * 2 + (kt - 6)) * 512 + l * 8] = fr;
            }
        }
    }
    if (t < 256) { hbufF[0][t] = (_Float16)0.f; hbufF[1][t] = (_Float16)0.f; }
    float cst = 0.f;               // cell state (threads t<256 own unit t)
    const int xbase = 32 * w + 4 * kg;
    __syncthreads();

    int buf = 0;
    for (int s = 0; s < SEQN; ++s) {
        const float* xr = xproj + (size_t)s * 1024;

        // acc init = xproj slice (C-operand): tile i rows 4*kg..4*kg+3
        f32x4 acc[8];
#pragma unroll
        for (int i = 0; i < 8; i++)
            acc[i] = *(const f32x4*)(xr + (i >> 1) * 256 + (i & 1) * 16 + xbase);

        // k-tiles 0..5: A from registers
#pragma unroll
        for (int kt = 0; kt < 6; kt++) {
            half8 b = *(const half8*)&hbufF[buf][kt * 32 + kg * 8];
#pragma unroll
            for (int i = 0; i < 8; i++)
                acc[i] = __builtin_amdgcn_mfma_f32_16x16x32_f16(Areg[i * 6 + kt], b, acc[i], 0, 0, 0);
        }
        // k-tiles 6..7: A from LDS (frag-major, conflict-free)
#pragma unroll
        for (int ktl = 0; ktl < 2; ktl++) {
            half8 b = *(const half8*)&hbufF[buf][(6 + ktl) * 32 + kg * 8];
#pragma unroll
            for (int i = 0; i < 8; i++) {
                half8 af = *(const half8*)&wlds[(w * 16 + i * 2 + ktl) * 512 + l * 8];
                acc[i] = __builtin_amdgcn_mfma_f32_16x16x32_f16(af, b, acc[i], 0, 0, 0);
            }
        }

        // col-0 lanes publish raw preacts: pre[gate][unit]
        if (row16 == 0) {
#pragma unroll
            for (int i = 0; i < 8; i++)
                *(f32x4*)&preF[(i >> 1) * 256 + 32 * w + 16 * (i & 1) + 4 * kg] = acc[i];
        }
        __syncthreads();

        // 256 threads: activations + cell update for unit t
        if (t < 256) {
            float fg = sigm(preF[t]);
            float ig = sigm(preF[256 + t]);
            float gg = tanh_f(preF[512 + t]);
            float og = sigm(preF[768 + t]);
            cst = fg * cst + ig * gg;
            float h = og * tanh_f(cst);
            h_all[s * 256 + t] = h;
            hbufF[buf ^ 1][t] = (_Float16)h;
        }
        __syncthreads();
        buf ^= 1;
    }
}

// ---------------------------------------------------------------------------
// logits[t][v] = h_all[t] . Wtag[v] + btag[v]   (64x64 tile / block, 4x4 micro)
// ---------------------------------------------------------------------------
__global__ __launch_bounds__(256) void logits_kernel(
    const float* __restrict__ h_all, const float* __restrict__ Wtag,
    const float* __restrict__ btag, float* __restrict__ out)
{
    __shared__ __align__(16) float At[64 * 68];
    __shared__ __align__(16) float Bt[64 * 68];
    const int tid = threadIdx.x;
    const int tx = tid & 15, ty = tid >> 4;
    const int t0 = blockIdx.y * 64, v0 = blockIdx.x * 64;
    float acc[4][4] = {};

    for (int kc = 0; kc < 256; kc += 64) {
        __syncthreads();
#pragma unroll
        for (int i = 0; i < 16; i++) {
            int idx = tid + i * 256;
            int rrow = idx >> 6, ccol = idx & 63;
            At[rrow * 68 + ccol] = h_all[(t0 + rrow) * 256 + kc + ccol];
            Bt[rrow * 68 + ccol] = Wtag[(size_t)(v0 + rrow) * 256 + kc + ccol];
        }
        __syncthreads();
#pragma unroll
        for (int k4 = 0; k4 < 16; k4++) {
            float4 av[4], bv[4];
#pragma unroll
            for (int i = 0; i < 4; i++) av[i] = *(const float4*)&At[(ty + 16 * i) * 68 + k4 * 4];
#pragma unroll
            for (int j = 0; j < 4; j++) bv[j] = *(const float4*)&Bt[(tx + 16 * j) * 68 + k4 * 4];
#pragma unroll
            for (int i = 0; i < 4; i++)
#pragma unroll
                for (int j = 0; j < 4; j++)
                    acc[i][j] += av[i].x * bv[j].x + av[i].y * bv[j].y +
                                 av[i].z * bv[j].z + av[i].w * bv[j].w;
        }
    }
#pragma unroll
    for (int j = 0; j < 4; j++) {
        float bb = btag[v0 + tx + 16 * j];
#pragma unroll
        for (int i = 0; i < 4; i++) {
            out[(size_t)(t0 + ty + 16 * i) * TAGSN + v0 + tx + 16 * j] = acc[i][j] + bb;
        }
    }
}

// ---------------------------------------------------------------------------
// in-place row-wise log_softmax over 8192 columns (one block per row)
// ---------------------------------------------------------------------------
__global__ __launch_bounds__(256) void lsm_kernel(float* __restrict__ out)
{
    const int row = blockIdx.x, tid = threadIdx.x;
    float* p = out + (size_t)row * TAGSN;
    float v[32];
#pragma unroll
    for (int j = 0; j < 32; j++) v[j] = p[tid + 256 * j];

    float m = -1e30f;
#pragma unroll
    for (int j = 0; j < 32; j++) m = fmaxf(m, v[j]);
#pragma unroll
    for (int off = 32; off; off >>= 1) m = fmaxf(m, __shfl_xor(m, off, 64));
    __shared__ float red[4];
    if ((tid & 63) == 0) red[tid >> 6] = m;
    __syncthreads();
    m = fmaxf(fmaxf(red[0], red[1]), fmaxf(red[2], red[3]));

    float s = 0.f;
#pragma unroll
    for (int j = 0; j < 32; j++) s += __expf(v[j] - m);
#pragma unroll
    for (int off = 32; off; off >>= 1) s += __shfl_xor(s, off, 64);
    __shared__ float red2[4];
    if ((tid & 63) == 0) red2[tid >> 6] = s;
    __syncthreads();
    s = (red2[0] + red2[1]) + (red2[2] + red2[3]);

    float lse = m + __logf(s);
#pragma unroll
    for (int j = 0; j < 32; j++) p[tid + 256 * j] = v[j] - lse;
}

// ---------------------------------------------------------------------------
extern "C" void kernel_launch(void* const* d_in, const int* in_sizes, int n_in,
                              void* d_out, int out_size, void* d_ws, size_t ws_size,
                              hipStream_t stream)
{
    const int*   sentence = (const int*)d_in[0];
    const float* emb  = (const float*)d_in[1];
    const float* Wf   = (const float*)d_in[2];
    const float* bf   = (const float*)d_in[3];
    const float* Wi   = (const float*)d_in[4];
    const float* bi   = (const float*)d_in[5];
    const float* Wg   = (const float*)d_in[6];
    const float* bg   = (const float*)d_in[7];
    const float* Wo   = (const float*)d_in[8];
    const float* bo   = (const float*)d_in[9];
    const float* Wtag = (const float*)d_in[10];
    const float* btag = (const float*)d_in[11];
    float* out = (float*)d_out;

    char* ws = (char*)d_ws;
    float* WxT   = (float*)(ws);                                      // 1 MiB
    float* bcat  = (float*)(ws + (1u << 20));                         // 4 KiB
    float* xproj = (float*)(ws + (1u << 20) + (1u << 16));            // 32 MiB
    float* h_all = (float*)(ws + (1u << 20) + (1u << 16) + (32u << 20)); // 8 MiB

    prep_kernel<<<1024, 256, 0, stream>>>(Wf, Wi, Wg, Wo, bf, bi, bg, bo, WxT, bcat);
    xproj_kernel<<<dim3(4, 256), 256, 0, stream>>>(sentence, emb, WxT, bcat, xproj);
    lstm_kernel<<<1, 512, 0, stream>>>(Wf, Wi, Wg, Wo, xproj, h_all);
    logits_kernel<<<dim3(128, 128), 256, 0, stream>>>(h_all, Wtag, btag, out);
    lsm_kernel<<<8192, 256, 0, stream>>>(out);
}

// Round 4
// 17676.408 us; speedup vs baseline: 4.5268x; 1.1342x over previous
//
#include <hip/hip_runtime.h>
#include <hip/hip_bf16.h>
#include <hip/hip_fp16.h>

#define VOCABN 50257
#define EMBEDN 256
#define HIDDENN 256
#define TAGSN 8192
#define SEQN 8192

typedef _Float16 half8 __attribute__((ext_vector_type(8)));
typedef float f32x4 __attribute__((ext_vector_type(4)));

__device__ __forceinline__ float sigm(float x) {
    x = fminf(fmaxf(x, -30.f), 30.f);
    return 1.f / (1.f + __expf(-x));
}

__device__ __forceinline__ float tanh_f(float x) {
    x = fminf(fmaxf(x, -15.f), 15.f);
    float e = __expf(-2.f * x);
    return (1.f - e) / (1.f + e);
}

// async global->LDS copy, 16 B per lane; lds base must be wave-uniform
__device__ __forceinline__ void gload_lds16(const float* g, float* l) {
    __builtin_amdgcn_global_load_lds(
        (const __attribute__((address_space(1))) unsigned int*)g,
        (__attribute__((address_space(3))) unsigned int*)l,
        16, 0, 0);
}

// ---------------------------------------------------------------------------
// prep: WxT[k][o] = W_gate(o)[o&255][k]  (transposed x-part for coalesced GEMM)
//       bcat[o]   = b_gate(o)[o&255]
// ---------------------------------------------------------------------------
__global__ __launch_bounds__(256) void prep_kernel(
    const float* __restrict__ Wf, const float* __restrict__ Wi,
    const float* __restrict__ Wg, const float* __restrict__ Wo,
    const float* __restrict__ bf, const float* __restrict__ bi,
    const float* __restrict__ bg, const float* __restrict__ bo,
    float* __restrict__ WxT, float* __restrict__ bcat)
{
    int idx = blockIdx.x * 256 + threadIdx.x;   // 0..262143
    int k = idx >> 10, o = idx & 1023;
    int g = o >> 8, r = o & 255;
    const float* W = (g == 0) ? Wf : (g == 1) ? Wi : (g == 2) ? Wg : Wo;
    WxT[idx] = W[r * 512 + k];
    if (idx < 1024) {
        const float* b = (g == 0) ? bf : (g == 1) ? bi : (g == 2) ? bg : bo;
        bcat[idx] = b[r];
    }
}

// ---------------------------------------------------------------------------
// xproj[s][o] = sum_k emb[sentence[s]][k] * WxT[k][o] + bcat[o]
// ---------------------------------------------------------------------------
__global__ __launch_bounds__(256) void xproj_kernel(
    const int* __restrict__ sentence, const float* __restrict__ emb,
    const float* __restrict__ WxT, const float* __restrict__ bcat,
    float* __restrict__ xproj)
{
    __shared__ __align__(16) float At[32 * 256];
    const int tid = threadIdx.x;
    const int s0 = blockIdx.y * 32;
    const int o = blockIdx.x * 256 + tid;

#pragma unroll
    for (int i = 0; i < 32; i++) {
        int idx = tid + i * 256;
        int srow = idx >> 8, c = idx & 255;
        At[idx] = emb[(size_t)sentence[s0 + srow] * 256 + c];
    }
    __syncthreads();

    float acc[32];
    float b = bcat[o];
#pragma unroll
    for (int i = 0; i < 32; i++) acc[i] = b;

    for (int k4 = 0; k4 < 64; k4++) {
        float4 w;
        w.x = WxT[(k4 * 4 + 0) * 1024 + o];
        w.y = WxT[(k4 * 4 + 1) * 1024 + o];
        w.z = WxT[(k4 * 4 + 2) * 1024 + o];
        w.w = WxT[(k4 * 4 + 3) * 1024 + o];
#pragma unroll
        for (int i = 0; i < 32; i++) {
            float4 a = *(const float4*)&At[i * 256 + k4 * 4];
            acc[i] += a.x * w.x + a.y * w.y + a.z * w.z + a.w * w.w;
        }
    }
#pragma unroll
    for (int i = 0; i < 32; i++)
        xproj[(size_t)(s0 + i) * 1024 + o] = acc[i];
}

// ---------------------------------------------------------------------------
// Persistent single-workgroup LSTM via MFMA (16x16x32 f16).
// 512 threads = 8 waves. Wave w owns units [32w, 32w+32) x all 4 gates
// = 8 output tiles of 16 rows. K = 256 = 8 k-tiles of 32:
//   k-tiles 0..5 : A-frags in AGPR-resident registers (MFMA reads natively)
//   k-tiles 6..7 : A-frags in LDS, frag-major (lane-linear, conflict-free)
// B-operand = h broadcast to all 16 cols (4 distinct 16B addrs/wave -> cheap).
// acc starts at 0; xproj is prefetched into an LDS double-buffer with
// global_load_lds at step top (drained for free by the first barrier after
// ~2000 cy of MFMA) and folded in by the 256 epilogue threads.
// D layout (HW-verified): col = lane&15 (replicated), row = (lane>>4)*4 + reg.
// ---------------------------------------------------------------------------
__global__ __launch_bounds__(512, 2) void lstm_kernel(
    const float* __restrict__ Wf, const float* __restrict__ Wi,
    const float* __restrict__ Wg, const float* __restrict__ Wo,
    const float* __restrict__ xproj, float* __restrict__ h_all)
{
    __shared__ __align__(16) _Float16 wlds[128 * 512];   // 128 KiB frag-major A (kt 6,7)
    __shared__ __align__(16) _Float16 hbufF[2][256];     // 1 KiB  dbuf h (f16)
    __shared__ __align__(16) float preF[4 * 256];        // 4 KiB  raw->act exchange
    __shared__ __align__(16) float ldsX[2][1024];        // 8 KiB  dbuf xproj row

    const int t = threadIdx.x;
    const int w = t >> 6;          // wave 0..7
    const int l = t & 63;          // lane
    const int row16 = l & 15;      // A row / D col
    const int kg = l >> 4;         // k-group 0..3

    const float* Wgate[4] = {Wf, Wi, Wg, Wo};

    // ---- one-time setup: A-frags into regs (kt<6) and LDS (kt 6,7) ----
    half8 Areg[48];                // [tile i][kt] = Areg[i*6+kt]
#pragma unroll
    for (int i = 0; i < 8; i++) {
        const int g = i >> 1, p = i & 1;
        const int row = 32 * w + 16 * p + row16;
        const float* base = Wgate[g] + row * 512 + 256 + 8 * kg;
#pragma unroll
        for (int kt = 0; kt < 8; kt++) {
            const float* src = base + kt * 32;
            half8 fr;
#pragma unroll
            for (int j = 0; j < 8; j++) fr[j] = (_Float16)src[j];
            if (kt < 6) {
                Areg[i * 6 + kt] = fr;
            } else {
                *(half8*)&wlds[(w * 16 + i * 2 + (kt - 6)) * 512 + l * 8] = fr;
            }
        }
    }
    if (t < 256) { hbufF[0][t] = (_Float16)0.f; hbufF[1][t] = (_Float16)0.f; }
    float cst = 0.f;               // cell state (threads t<256 own unit t)

    // prologue: prefetch xproj row 0 into ldsX[0] (drained by the barrier)
    if (t < 256)
        gload_lds16(xproj + t * 4, &ldsX[0][(t >> 6) * 256]);
    __syncthreads();

    int buf = 0;
    for (int s = 0; s < SEQN; ++s) {
        // prefetch next step's xproj row (async; drained at first barrier)
        if (t < 256 && s + 1 < SEQN)
            gload_lds16(xproj + (size_t)(s + 1) * 1024 + t * 4,
                        &ldsX[buf ^ 1][(t >> 6) * 256]);

        f32x4 acc[8];
#pragma unroll
        for (int i = 0; i < 8; i++) acc[i] = f32x4{0.f, 0.f, 0.f, 0.f};

        // k-tiles 0..5: A from registers (AGPR-resident)
#pragma unroll
        for (int kt = 0; kt < 6; kt++) {
            half8 b = *(const half8*)&hbufF[buf][kt * 32 + kg * 8];
#pragma unroll
            for (int i = 0; i < 8; i++)
                acc[i] = __builtin_amdgcn_mfma_f32_16x16x32_f16(Areg[i * 6 + kt], b, acc[i], 0, 0, 0);
        }
        // k-tiles 6..7: A from LDS (frag-major, conflict-free)
#pragma unroll
        for (int ktl = 0; ktl < 2; ktl++) {
            half8 b = *(const half8*)&hbufF[buf][(6 + ktl) * 32 + kg * 8];
#pragma unroll
            for (int i = 0; i < 8; i++) {
                half8 af = *(const half8*)&wlds[(w * 16 + i * 2 + ktl) * 512 + l * 8];
                acc[i] = __builtin_amdgcn_mfma_f32_16x16x32_f16(af, b, acc[i], 0, 0, 0);
            }
        }

        // col-0 lanes publish raw preacts: pre[gate][unit]
        if (row16 == 0) {
#pragma unroll
            for (int i = 0; i < 8; i++)
                *(f32x4*)&preF[(i >> 1) * 256 + 32 * w + 16 * (i & 1) + 4 * kg] = acc[i];
        }
        __syncthreads();   // B1: preF visible; xp prefetch drained (vmcnt 0)

        // 256 threads: add xp, activations + cell update for unit t
        if (t < 256) {
            const float* xq = ldsX[buf];
            float fg = sigm(preF[t] + xq[t]);
            float ig = sigm(preF[256 + t] + xq[256 + t]);
            float gg = tanh_f(preF[512 + t] + xq[512 + t]);
            float og = sigm(preF[768 + t] + xq[768 + t]);
            cst = fg * cst + ig * gg;
            float h = og * tanh_f(cst);
            h_all[s * 256 + t] = h;
            hbufF[buf ^ 1][t] = (_Float16)h;
        }
        __syncthreads();   // B2: new h visible
        buf ^= 1;
    }
}

// ---------------------------------------------------------------------------
// logits[t][v] = h_all[t] . Wtag[v] + btag[v]   (64x64 tile / block, 4x4 micro)
// ---------------------------------------------------------------------------
__global__ __launch_bounds__(256) void logits_kernel(
    const float* __restrict__ h_all, const float* __restrict__ Wtag,
    const float* __restrict__ btag, float* __restrict__ out)
{
    __shared__ __align__(16) float At[64 * 68];
    __shared__ __align__(16) float Bt[64 * 68];
    const int tid = threadIdx.x;
    const int tx = tid & 15, ty = tid >> 4;
    const int t0 = blockIdx.y * 64, v0 = blockIdx.x * 64;
    float acc[4][4] = {};

    for (int kc = 0; kc < 256; kc += 64) {
        __syncthreads();
#pragma unroll
        for (int i = 0; i < 16; i++) {
            int idx = tid + i * 256;
            int rrow = idx >> 6, ccol = idx & 63;
            At[rrow * 68 + ccol] = h_all[(t0 + rrow) * 256 + kc + ccol];
            Bt[rrow * 68 + ccol] = Wtag[(size_t)(v0 + rrow) * 256 + kc + ccol];
        }
        __syncthreads();
#pragma unroll
        for (int k4 = 0; k4 < 16; k4++) {
            float4 av[4], bv[4];
#pragma unroll
            for (int i = 0; i < 4; i++) av[i] = *(const float4*)&At[(ty + 16 * i) * 68 + k4 * 4];
#pragma unroll
            for (int j = 0; j < 4; j++) bv[j] = *(const float4*)&Bt[(tx + 16 * j) * 68 + k4 * 4];
#pragma unroll
            for (int i = 0; i < 4; i++)
#pragma unroll
                for (int j = 0; j < 4; j++)
                    acc[i][j] += av[i].x * bv[j].x + av[i].y * bv[j].y +
                                 av[i].z * bv[j].z + av[i].w * bv[j].w;
        }
    }
#pragma unroll
    for (int j = 0; j < 4; j++) {
        float bb = btag[v0 + tx + 16 * j];
#pragma unroll
        for (int i = 0; i < 4; i++) {
            out[(size_t)(t0 + ty + 16 * i) * TAGSN + v0 + tx + 16 * j] = acc[i][j] + bb;
        }
    }
}

// ---------------------------------------------------------------------------
// in-place row-wise log_softmax over 8192 columns (one block per row)
// ---------------------------------------------------------------------------
__global__ __launch_bounds__(256) void lsm_kernel(float* __restrict__ out)
{
    const int row = blockIdx.x, tid = threadIdx.x;
    float* p = out + (size_t)row * TAGSN;
    float v[32];
#pragma unroll
    for (int j = 0; j < 32; j++) v[j] = p[tid + 256 * j];

    float m = -1e30f;
#pragma unroll
    for (int j = 0; j < 32; j++) m = fmaxf(m, v[j]);
#pragma unroll
    for (int off = 32; off; off >>= 1) m = fmaxf(m, __shfl_xor(m, off, 64));
    __shared__ float red[4];
    if ((tid & 63) == 0) red[tid >> 6] = m;
    __syncthreads();
    m = fmaxf(fmaxf(red[0], red[1]), fmaxf(red[2], red[3]));

    float s = 0.f;
#pragma unroll
    for (int j = 0; j < 32; j++) s += __expf(v[j] - m);
#pragma unroll
    for (int off = 32; off; off >>= 1) s += __shfl_xor(s, off, 64);
    __shared__ float red2[4];
    if ((tid & 63) == 0) red2[tid >> 6] = s;
    __syncthreads();
    s = (red2[0] + red2[1]) + (red2[2] + red2[3]);

    float lse = m + __logf(s);
#pragma unroll
    for (int j = 0; j < 32; j++) p[tid + 256 * j] = v[j] - lse;
}

// ---------------------------------------------------------------------------
extern "C" void kernel_launch(void* const* d_in, const int* in_sizes, int n_in,
                              void* d_out, int out_size, void* d_ws, size_t ws_size,
                              hipStream_t stream)
{
    const int*   sentence = (const int*)d_in[0];
    const float* emb  = (const float*)d_in[1];
    const float* Wf   = (const float*)d_in[2];
    const float* bf   = (const float*)d_in[3];
    const float* Wi   = (const float*)d_in[4];
    const float* bi   = (const float*)d_in[5];
    const float* Wg   = (const float*)d_in[6];
    const float* bg   = (const float*)d_in[7];
    const float* Wo   = (const float*)d_in[8];
    const float* bo   = (const float*)d_in[9];
    const float* Wtag = (const float*)d_in[10];
    const float* btag = (const float*)d_in[11];
    float* out = (float*)d_out;

    char* ws = (char*)d_ws;
    float* WxT   = (float*)(ws);                                      // 1 MiB
    float* bcat  = (float*)(ws + (1u << 20));                         // 4 KiB
    float* xproj = (float*)(ws + (1u << 20) + (1u << 16));            // 32 MiB
    float* h_all = (float*)(ws + (1u << 20) + (1u << 16) + (32u << 20)); // 8 MiB

    prep_kernel<<<1024, 256, 0, stream>>>(Wf, Wi, Wg, Wo, bf, bi, bg, bo, WxT, bcat);
    xproj_kernel<<<dim3(4, 256), 256, 0, stream>>>(sentence, emb, WxT, bcat, xproj);
    lstm_kernel<<<1, 512, 0, stream>>>(Wf, Wi, Wg, Wo, xproj, h_all);
    logits_kernel<<<dim3(128, 128), 256, 0, stream>>>(h_all, Wtag, btag, out);
    lsm_kernel<<<8192, 256, 0, stream>>>(out);
}